// Round 8
// baseline (813.025 us; speedup 1.0000x reference)
//
#include <hip/hip_runtime.h>
#include <cfloat>

// ClDiceLoss (B=2, C=1, 192^3) fp32.
// Fused soft-skeletonize iteration, 1-barrier-per-plane pipeline.
// Round-8: (a) conflict-free 16-quad LDS layout — round 6/7's constant
// 2.07e7 conflicts came from the 17-quad row mapping (8-lane b128 phase
// groups straddling a row restart re-hit bank group 4r+4 at a different
// address). 16 quads/row = exactly 2 phase groups, never wraps; the 68-wide
// tail folds into q==15 threads (their ld8 already spans cols 60..67).
// (b) register-staged global prefetch: step s commits (ds_write) the plane
// fetched in step s-1 and fetches z+2 into registers, so no vmcnt stall
// feeds the per-step barrier. (c) 8 blocks/CU.
//   step s (z = z0+s):
//     A: commit x(z+1) from regs; fetch x(z+2) -> regs;
//        M(z-1) = 7pt cross-min -> ms[(z-1)&1]
//     barrier
//     B: P(z-1) = 3x3 in-plane max of M(z-1); M-center + x(z-1) to registers;
//        emit out(z-2) = relu(x - relu(max(P(z-3..z-1)) - M(z-2))) from history.
// Boundary: M at out-of-volume (y,x) = -FLT_MAX (exact -inf-pad reduce_window
// semantics); z edges via plane-index guards; clamped x loads harmless (min).
// Both chains in one dispatch when ws allows; 5th iteration fuses reductions.

constexpr int D = 192, H = 192, W = 192, B = 2;
constexpr int HW = H * W;
constexpr int VOL = D * HW;
constexpr int TX = 64, TY = 8;
constexpr int CZ = 32, NCH = 6;
constexpr int MAXPART = 3 * 24 * NCH * B;   // 864 blocks per chain

struct Eight { float a[8]; };
__device__ __forceinline__ Eight ld8(const float* p) {  // p 16B-aligned
  Eight e;
  const float4 u = *(const float4*)p;
  const float4 v = *(const float4*)(p + 4);
  e.a[0] = u.x; e.a[1] = u.y; e.a[2] = u.z; e.a[3] = u.w;
  e.a[4] = v.x; e.a[5] = v.y; e.a[6] = v.z; e.a[7] = v.w;
  return e;
}
__device__ __forceinline__ float max3(float a, float b, float c) {
  return fmaxf(fmaxf(a, b), c);
}

__global__ __launch_bounds__(256, 8) void skel_iter(
    const float* __restrict__ srcA, float* __restrict__ dstA,
    const float* __restrict__ othA, double* __restrict__ partA,
    const float* __restrict__ srcB, float* __restrict__ dstB,
    const float* __restrict__ othB, double* __restrict__ partB,
    int cz, int nch, int last) {
  __shared__ alignas(16) float xs[4][12 * 68];  // x planes, halo 2 (13.1 KB)
  __shared__ alignas(16) float ms[2][10 * 68];  // M parity planes (5.4 KB)
  __shared__ double red[8];

  const int tid = threadIdx.x;
  const int wave = tid >> 6;
  const int lane = tid & 63;
  const int x0 = blockIdx.x * TX;
  const int y0 = blockIdx.y * TY;
  int t = blockIdx.z;
  const int chunk = t % nch; t /= nch;
  const int b = t % B;
  const int chain = t / B;
  const int z0 = chunk * cz;

  const float* vs = (chain ? srcB : srcA) + (size_t)b * VOL;
  float* vd = (chain ? dstB : dstA) + (size_t)b * VOL;
  const float* vo = (chain ? othB : othA) + (size_t)b * VOL;
  double* part = chain ? partB : partA;

  // ---- loader: 192 threads, row = tid>>4 (0..11), q = tid&15 ----
  // main cells 4q..4q+3 (cols 0..63); q==15 additionally cols 64..67.
  const int l_row = tid >> 4, l_q = tid & 15;
  const int l_gy = min(max(y0 - 2 + l_row, 0), H - 1) * W;
  const int l_gx0 = x0 - 2 + 4 * l_q;
  const bool l_dup0 = (l_gx0 < 0);             // left edge clamp-dup
  const int l_a0 = l_gy + (l_dup0 ? 0 : l_gx0);
  const int l_a1 = l_gy + l_gx0 + 2;           // never OOB
  const bool l_ext = (l_q == 15) && (tid < 192);
  const int l_a2 = l_gy + x0 + 62;             // cols 64,65  (gx x0+62,63)
  const bool l_dup3 = (x0 + 65 > W - 1);       // right edge (x0==128)
  const int l_a3 = l_gy + (l_dup3 ? (W - 1) : (x0 + 64));
  const int l_lds = l_row * 68 + 4 * l_q;

  auto fetch = [&](int z, float4& r0, float4& r1) {
    if (tid < 192) {
      const int zc = min(max(z, 0), D - 1);
      const float* base = vs + (size_t)zc * HW;
      float2 p0, p1;
      if (l_dup0) { const float v = base[l_a0]; p0 = {v, v}; }
      else p0 = *(const float2*)(base + l_a0);
      p1 = *(const float2*)(base + l_a1);
      r0 = {p0.x, p0.y, p1.x, p1.y};
      if (l_ext) {
        const float2 p2 = *(const float2*)(base + l_a2);
        float2 p3;
        if (l_dup3) { const float v = base[l_a3]; p3 = {v, v}; }
        else p3 = *(const float2*)(base + l_a3);
        r1 = {p2.x, p2.y, p3.x, p3.y};
      }
    }
  };
  auto commit = [&](int z, const float4& r0, const float4& r1) {
    if (tid < 192) {
      float* xp = xs[(z + 1024) & 3];
      *(float4*)&xp[l_lds] = r0;
      if (l_ext) *(float4*)&xp[l_lds + 4] = r1;
    }
  };

  // ---- M stage: 160 threads, row = tid>>4 (0..9), q = tid&15 ----
  // main cells c0..c0+3; q==15 additionally cells 64,65 (ld8 spans 60..67).
  const int m_row = tid >> 4, m_q = tid & 15;
  const int m_c0 = 4 * m_q;
  const bool m_rok = ((unsigned)(y0 - 1 + m_row) < (unsigned)H);
  bool m_okl[6];
  #pragma unroll
  for (int i = 0; i < 6; ++i)
    m_okl[i] = m_rok && ((unsigned)(x0 - 1 + m_c0 + i) < (unsigned)W);
  const bool m_ext = (m_q == 15) && (tid < 160);
  const int m_xc = (m_row + 1) * 68 + m_c0;
  const int m_xu = m_row * 68 + m_c0;
  const int m_xd = (m_row + 2) * 68 + m_c0;
  const int m_o = m_row * 68 + m_c0;

  auto m_stage = [&](int z) {   // M(z) -> ms[z&1]
    if (tid < 160) {
      const float* xc = xs[(z + 1024) & 3];
      const float* xm = xs[(z + 1023) & 3];
      const float* xq = xs[(z + 1025) & 3];
      const Eight c = ld8(xc + m_xc);
      const Eight u = ld8(xc + m_xu);
      const Eight d = ld8(xc + m_xd);
      const Eight zm = ld8(xm + m_xc);
      const Eight zq = ld8(xq + m_xc);
      float v[6];
      #pragma unroll
      for (int i = 0; i < 6; ++i) {
        v[i] = fminf(fminf(c.a[i], c.a[i + 1]), c.a[i + 2]);
        v[i] = fminf(v[i], fminf(u.a[i + 1], d.a[i + 1]));
        v[i] = fminf(v[i], fminf(zm.a[i + 1], zq.a[i + 1]));
        v[i] = m_okl[i] ? v[i] : -FLT_MAX;
      }
      float* mp = ms[z & 1];
      *(float4*)&mp[m_o] = {v[0], v[1], v[2], v[3]};
      if (m_ext) *(float2*)&mp[m_o + 4] = {v[4], v[5]};
    }
  };

  // ---- B: 128 threads, cell quad (row 0..7, cols 4*(tid&15)..+3) ----
  const int b_r = tid >> 4;
  const int b_c0 = 4 * (tid & 15);
  const int b_m0 = b_r * 68 + b_c0;
  const int b_x4 = (b_r + 2) * 68 + b_c0;     // x cells at elems 2..5
  const int b_off = (y0 + b_r) * W + x0 + b_c0;

  float p_mm[4], p_m[4], m_prev[4], x_prev[4];
  float sp = 0.0f, ss = 0.0f;
  float4 sr0, sr1;

  // Prologue: fetch planes z0-2..z0 (overlapped), commit, prefetch z0+1.
  {
    float4 a0, a1, b0, b1, c0, c1;
    fetch(z0 - 2, a0, a1);
    fetch(z0 - 1, b0, b1);
    fetch(z0, c0, c1);
    commit(z0 - 2, a0, a1);
    commit(z0 - 1, b0, b1);
    commit(z0, c0, c1);
    fetch(z0 + 1, sr0, sr1);
  }
  __syncthreads();

  for (int s = 0; s <= cz + 1; ++s) {
    const int z = z0 + s;
    // ---- phase A ----
    if (s <= cz) {
      commit(z + 1, sr0, sr1);
      if (s <= cz - 1) fetch(z + 2, sr0, sr1);
    }
    m_stage(z - 1);
    __syncthreads();
    // ---- phase B ----
    if (tid < 128) {
      const float* mp = ms[(z - 1) & 1];
      float pc[4], mc[4];
      {
        const Eight r0 = ld8(mp + b_m0);
        #pragma unroll
        for (int i = 0; i < 4; ++i)
          pc[i] = max3(r0.a[i], r0.a[i + 1], r0.a[i + 2]);
        const Eight r1 = ld8(mp + b_m0 + 68);
        #pragma unroll
        for (int i = 0; i < 4; ++i) {
          mc[i] = r1.a[i + 1];
          pc[i] = fmaxf(pc[i], max3(r1.a[i], r1.a[i + 1], r1.a[i + 2]));
        }
        const Eight r2 = ld8(mp + b_m0 + 136);
        #pragma unroll
        for (int i = 0; i < 4; ++i)
          pc[i] = fmaxf(pc[i], max3(r2.a[i], r2.a[i + 1], r2.a[i + 2]));
      }
      const Eight xv = ld8(xs[(z + 1023) & 3] + b_x4);  // x plane z-1
      if (s >= 2) {
        const int zo = z - 2;
        const bool zlo = (zo > 0), zhi = (zo < D - 1);
        float o[4];
        #pragma unroll
        for (int i = 0; i < 4; ++i) {
          float p = p_m[i];
          if (zlo) p = fmaxf(p, p_mm[i]);
          if (zhi) p = fmaxf(p, pc[i]);
          const float contour = fmaxf(p - m_prev[i], 0.0f);
          o[i] = fmaxf(x_prev[i] - contour, 0.0f);
        }
        const size_t g = (size_t)zo * HW + b_off;
        if (last) {
          const float4 w = *(const float4*)(vo + g);
          sp += o[0] * w.x + o[1] * w.y + o[2] * w.z + o[3] * w.w;
          ss += o[0] + o[1] + o[2] + o[3];
        } else {
          *(float4*)(vd + g) = {o[0], o[1], o[2], o[3]};
        }
      }
      #pragma unroll
      for (int i = 0; i < 4; ++i) {
        p_mm[i] = p_m[i];
        p_m[i] = pc[i];
        m_prev[i] = mc[i];
        x_prev[i] = xv.a[i + 2];
      }
    }
  }

  if (last) {
    #pragma unroll
    for (int off = 32; off > 0; off >>= 1) {
      sp += __shfl_down(sp, off, 64);
      ss += __shfl_down(ss, off, 64);
    }
    if (lane == 0) {
      red[wave] = (double)sp;
      red[4 + wave] = (double)ss;
    }
    __syncthreads();
    if (tid == 0) {
      const double a = red[0] + red[1] + red[2] + red[3];
      const double s2 = red[4] + red[5] + red[6] + red[7];
      const int lin = ((b * nch + chunk) * 24 + blockIdx.y) * 3 + blockIdx.x;
      part[2 * lin] = a;
      part[2 * lin + 1] = s2;
    }
  }
}

__global__ void finalize_kernel(const double* __restrict__ pa,
                                const double* __restrict__ pb,
                                float* __restrict__ out, int npart) {
  __shared__ double red[4][4];
  double s[4] = {0, 0, 0, 0};
  for (int i = threadIdx.x; i < npart; i += 256) {
    s[0] += pa[2 * i];
    s[1] += pa[2 * i + 1];
    s[2] += pb[2 * i];
    s[3] += pb[2 * i + 1];
  }
  #pragma unroll
  for (int off = 32; off > 0; off >>= 1)
    #pragma unroll
    for (int j = 0; j < 4; ++j) s[j] += __shfl_down(s[j], off, 64);
  const int wave = threadIdx.x >> 6, lane = threadIdx.x & 63;
  if (lane == 0)
    for (int j = 0; j < 4; ++j) red[j][wave] = s[j];
  __syncthreads();
  if (threadIdx.x == 0) {
    double t[4];
    for (int j = 0; j < 4; ++j)
      t[j] = red[j][0] + red[j][1] + red[j][2] + red[j][3];
    const double recall = (t[0] + 1e-12) / (t[1] + 1e-12);
    const double accv = (t[2] + 1e-12) / (t[3] + 1e-12);
    const double cldice = 2.0 * recall * accv / (recall + accv);
    out[0] = (float)(1.0 - cldice);
  }
}

extern "C" void kernel_launch(void* const* d_in, const int* in_sizes, int n_in,
                              void* d_out, int out_size, void* d_ws, size_t ws_size,
                              hipStream_t stream) {
  const float* pred = (const float*)d_in[0];
  const float* target = (const float*)d_in[1];
  float* out = (float*)d_out;
  const size_t NT = (size_t)VOL * B;

  const size_t need_merged = 4 * NT * sizeof(float) + 4 * MAXPART * sizeof(double);
  const dim3 blk(256, 1, 1);
  const int cz = CZ, nch = NCH;
  const int npart = 3 * 24 * nch * B;   // 864 per chain

  if (ws_size >= need_merged) {
    float* a0 = (float*)d_ws;
    float* a1 = a0 + NT;
    float* c0 = a1 + NT;
    float* c1 = c0 + NT;
    double* pA = (double*)(c1 + NT);
    double* pB = pA + 2 * MAXPART;
    const dim3 grd(3, 24, nch * B * 2);   // 1728 blocks
    skel_iter<<<grd, blk, 0, stream>>>(target, a0, pred, pA, pred, c0, target, pB, cz, nch, 0);
    skel_iter<<<grd, blk, 0, stream>>>(a0, a1, pred, pA, c0, c1, target, pB, cz, nch, 0);
    skel_iter<<<grd, blk, 0, stream>>>(a1, a0, pred, pA, c1, c0, target, pB, cz, nch, 0);
    skel_iter<<<grd, blk, 0, stream>>>(a0, a1, pred, pA, c0, c1, target, pB, cz, nch, 0);
    skel_iter<<<grd, blk, 0, stream>>>(a1, a0, pred, pA, c1, c0, target, pB, cz, nch, 1);
    finalize_kernel<<<1, 256, 0, stream>>>(pA, pB, out, npart);
  } else {
    float* b0 = (float*)d_ws;
    float* b1 = b0 + NT;
    double* pA = (double*)(b1 + NT);
    double* pB = pA + 2 * MAXPART;
    const dim3 grd(3, 24, nch * B);
    skel_iter<<<grd, blk, 0, stream>>>(target, b0, pred, pA, nullptr, nullptr, nullptr, nullptr, cz, nch, 0);
    skel_iter<<<grd, blk, 0, stream>>>(b0, b1, pred, pA, nullptr, nullptr, nullptr, nullptr, cz, nch, 0);
    skel_iter<<<grd, blk, 0, stream>>>(b1, b0, pred, pA, nullptr, nullptr, nullptr, nullptr, cz, nch, 0);
    skel_iter<<<grd, blk, 0, stream>>>(b0, b1, pred, pA, nullptr, nullptr, nullptr, nullptr, cz, nch, 0);
    skel_iter<<<grd, blk, 0, stream>>>(b1, b0, pred, pA, nullptr, nullptr, nullptr, nullptr, cz, nch, 1);
    skel_iter<<<grd, blk, 0, stream>>>(pred, b0, target, pB, nullptr, nullptr, nullptr, nullptr, cz, nch, 0);
    skel_iter<<<grd, blk, 0, stream>>>(b0, b1, target, pB, nullptr, nullptr, nullptr, nullptr, cz, nch, 0);
    skel_iter<<<grd, blk, 0, stream>>>(b1, b0, target, pB, nullptr, nullptr, nullptr, nullptr, cz, nch, 0);
    skel_iter<<<grd, blk, 0, stream>>>(b0, b1, target, pB, nullptr, nullptr, nullptr, nullptr, cz, nch, 0);
    skel_iter<<<grd, blk, 0, stream>>>(b1, b0, target, pB, nullptr, nullptr, nullptr, nullptr, cz, nch, 1);
    finalize_kernel<<<1, 256, 0, stream>>>(pA, pB, out, npart);
  }
}

// Round 9
// 669.854 us; speedup vs baseline: 1.2137x; 1.2137x over previous
//
#include <hip/hip_runtime.h>
#include <cfloat>

// ClDiceLoss (B=2, C=1, 192^3) fp32.
// Fused soft-skeletonize iteration, 1-barrier-per-plane pipeline.
// Round-9: DS-instruction diet. Round 6-8 were DS-issue bound (~53 b128
// wave-instrs/block-step; the constant 2.07e7 "conflicts" are b128's
// inherent 4-word/bank reuse, not fixable). Changes:
//  (a) M-thread row map shifted so tid<128 computes exactly the M row and
//      center-x row its own phase-B cell needs -> m_prev/x_prev histories
//      are register moves; phase-B ms/xs reads deleted.
//  (b) 3-deep register cache (Eight c_mm,c_m) of the center x-row: M-stage
//      reads only u-row, d-row, new-plane center row (3 ld8, was 5).
//  (c) R = max3_x(M) computed in M-thread registers (6 M cells cover R cols
//      c0+1..c0+4 exactly); only rs (10x64) is stored -- ms array deleted.
//      Phase B = 3 b128 reads of rs.
//  (d) launch_bounds (256,6): round 8's (256,8) capped VGPRs at 32 and
//      spilled to scratch (WRITE_SIZE 110->203 MB). DS-throughput bound, so
//      6 blocks/CU suffices.
// Boundary: M at out-of-volume (y,x) = -FLT_MAX (exact -inf-pad
// reduce_window semantics); z edges via plane-index guards in emit; clamped
// x loads harmless for min. Both chains in one dispatch when ws allows; the
// 5th iteration fuses the reductions.

constexpr int D = 192, H = 192, W = 192, B = 2;
constexpr int HW = H * W;
constexpr int VOL = D * HW;
constexpr int TX = 64, TY = 8;
constexpr int CZ = 32, NCH = 6;
constexpr int MAXPART = 3 * 24 * NCH * B;   // 864 blocks per chain

struct Eight { float a[8]; };
__device__ __forceinline__ Eight ld8(const float* p) {  // p 16B-aligned
  Eight e;
  const float4 u = *(const float4*)p;
  const float4 v = *(const float4*)(p + 4);
  e.a[0] = u.x; e.a[1] = u.y; e.a[2] = u.z; e.a[3] = u.w;
  e.a[4] = v.x; e.a[5] = v.y; e.a[6] = v.z; e.a[7] = v.w;
  return e;
}
__device__ __forceinline__ float max3(float a, float b, float c) {
  return fmaxf(fmaxf(a, b), c);
}

__global__ __launch_bounds__(256, 6) void skel_iter(
    const float* __restrict__ srcA, float* __restrict__ dstA,
    const float* __restrict__ othA, double* __restrict__ partA,
    const float* __restrict__ srcB, float* __restrict__ dstB,
    const float* __restrict__ othB, double* __restrict__ partB,
    int cz, int nch, int last) {
  __shared__ alignas(16) float xs[4][12 * 68];  // x planes, halo 2 (13.1 KB)
  __shared__ alignas(16) float rs[2][10 * 64];  // R parity planes (5.1 KB)
  __shared__ double red[8];

  const int tid = threadIdx.x;
  const int wave = tid >> 6;
  const int lane = tid & 63;
  const int x0 = blockIdx.x * TX;
  const int y0 = blockIdx.y * TY;
  int t = blockIdx.z;
  const int chunk = t % nch; t /= nch;
  const int b = t % B;
  const int chain = t / B;
  const int z0 = chunk * cz;

  const float* vs = (chain ? srcB : srcA) + (size_t)b * VOL;
  float* vd = (chain ? dstB : dstA) + (size_t)b * VOL;
  const float* vo = (chain ? othB : othA) + (size_t)b * VOL;
  double* part = chain ? partB : partA;

  // ---- loader: 192 threads, row = tid>>4 (0..11), q = tid&15 ----
  const int l_row = tid >> 4, l_q = tid & 15;
  const int l_gy = min(max(y0 - 2 + l_row, 0), H - 1) * W;
  const int l_gx0 = x0 - 2 + 4 * l_q;
  const bool l_dup0 = (l_gx0 < 0);             // left edge clamp-dup
  const int l_a0 = l_gy + (l_dup0 ? 0 : l_gx0);
  const int l_a1 = l_gy + l_gx0 + 2;           // never OOB
  const bool l_ext = (l_q == 15) && (tid < 192);
  const int l_a2 = l_gy + x0 + 62;             // cols 64,65 (gx x0+62,63)
  const bool l_dup3 = (x0 + 65 > W - 1);       // right edge (x0==128)
  const int l_a3 = l_gy + (l_dup3 ? (W - 1) : (x0 + 64));
  const int l_lds = l_row * 68 + 4 * l_q;

  auto fetch = [&](int z, float4& r0, float4& r1) {
    if (tid < 192) {
      const int zc = min(max(z, 0), D - 1);
      const float* base = vs + (size_t)zc * HW;
      float2 p0, p1;
      if (l_dup0) { const float v = base[l_a0]; p0 = {v, v}; }
      else p0 = *(const float2*)(base + l_a0);
      p1 = *(const float2*)(base + l_a1);
      r0 = {p0.x, p0.y, p1.x, p1.y};
      if (l_ext) {
        const float2 p2 = *(const float2*)(base + l_a2);
        float2 p3;
        if (l_dup3) { const float v = base[l_a3]; p3 = {v, v}; }
        else p3 = *(const float2*)(base + l_a3);
        r1 = {p2.x, p2.y, p3.x, p3.y};
      }
    }
  };
  auto commit = [&](int z, const float4& r0, const float4& r1) {
    if (tid < 192) {
      float* xp = xs[(z + 1024) & 3];
      *(float4*)&xp[l_lds] = r0;
      if (l_ext) *(float4*)&xp[l_lds + 4] = r1;
    }
  };

  // ---- M stage: 160 threads. Row map shifted: tid<128 -> row 1+(tid>>4)
  // (so its M cells / center-x row are exactly its phase-B cell's needs);
  // tid 128..143 -> row 0, tid 144..159 -> row 9 (halo rows).
  const int m_row = (tid < 128) ? (1 + (tid >> 4)) : ((tid < 144) ? 0 : 9);
  const int m_q = tid & 15;
  const int m_c0 = 4 * m_q;
  const bool m_rok = ((unsigned)(y0 - 1 + m_row) < (unsigned)H);
  bool m_okl[6];
  #pragma unroll
  for (int i = 0; i < 6; ++i)
    m_okl[i] = m_rok && ((unsigned)(x0 - 1 + m_c0 + i) < (unsigned)W);
  const int m_xu = m_row * 68 + m_c0;          // x row m_row
  const int m_xd = (m_row + 2) * 68 + m_c0;    // x row m_row+2
  const int m_xc = (m_row + 1) * 68 + m_c0;    // center x row m_row+1
  const int m_rs = m_row * 64 + m_c0;          // rs[row][c0] = R at ms col c0+1

  // ---- B: 128 threads, cell quad (row b_r 0..7, cols b_c0..b_c0+3) ----
  const int b_r = tid >> 4;
  const int b_c0 = 4 * (tid & 15);
  const int b_rs = b_r * 64 + b_c0;
  const int b_off = (y0 + b_r) * W + x0 + b_c0;

  Eight c_mm, c_m;                 // center-x rows, planes z-2 / z-1
  float p_mm[4], p_m[4], m_prev[4], x_prev[4];
  float sp = 0.0f, ss = 0.0f;
  float4 sr0, sr1;

  // Prologue: commit planes z0-2..z0, prefetch z0+1, seed center cache.
  {
    float4 a0, a1, b0, b1, c0, c1;
    fetch(z0 - 2, a0, a1);
    fetch(z0 - 1, b0, b1);
    fetch(z0, c0, c1);
    commit(z0 - 2, a0, a1);
    commit(z0 - 1, b0, b1);
    commit(z0, c0, c1);
    fetch(z0 + 1, sr0, sr1);
  }
  __syncthreads();
  if (tid < 160) {
    c_mm = ld8(xs[(z0 + 1022) & 3] + m_xc);   // center(z0-2)
    c_m  = ld8(xs[(z0 + 1023) & 3] + m_xc);   // center(z0-1)
  }

  for (int s = 0; s <= cz + 1; ++s) {
    const int z = z0 + s;
    float v[6];
    // ---- phase A ----
    if (s <= cz) {
      commit(z + 1, sr0, sr1);
      if (s <= cz - 1) fetch(z + 2, sr0, sr1);
    }
    if (tid < 160) {   // M(z-1) in regs; R -> rs[(z-1)&1]
      const float* xz  = xs[(z + 1023) & 3];  // plane z-1 (u/d rows)
      const float* xzp = xs[(z + 1024) & 3];  // plane z (fresh center)
      const Eight fr = ld8(xzp + m_xc);
      const Eight u  = ld8(xz + m_xu);
      const Eight d  = ld8(xz + m_xd);
      #pragma unroll
      for (int i = 0; i < 6; ++i) {
        float tmin = fminf(fminf(c_m.a[i], c_m.a[i + 1]), c_m.a[i + 2]);
        tmin = fminf(tmin, fminf(u.a[i + 1], d.a[i + 1]));
        tmin = fminf(tmin, fminf(c_mm.a[i + 1], fr.a[i + 1]));
        v[i] = m_okl[i] ? tmin : -FLT_MAX;
      }
      *(float4*)&rs[(z - 1) & 1][m_rs] =
          {max3(v[0], v[1], v[2]), max3(v[1], v[2], v[3]),
           max3(v[2], v[3], v[4]), max3(v[3], v[4], v[5])};
      c_mm = c_m;
      c_m = fr;
    }
    __syncthreads();
    // ---- phase B ----
    if (tid < 128) {
      const float* rp = rs[(z - 1) & 1];
      const float4 ra = *(const float4*)&rp[b_rs];
      const float4 rb = *(const float4*)&rp[b_rs + 64];
      const float4 rc = *(const float4*)&rp[b_rs + 128];
      const float pc[4] = {max3(ra.x, rb.x, rc.x), max3(ra.y, rb.y, rc.y),
                           max3(ra.z, rb.z, rc.z), max3(ra.w, rb.w, rc.w)};
      if (s >= 2) {
        const int zo = z - 2;
        const bool zlo = (zo > 0), zhi = (zo < D - 1);
        float o[4];
        #pragma unroll
        for (int i = 0; i < 4; ++i) {
          float p = p_m[i];
          if (zlo) p = fmaxf(p, p_mm[i]);
          if (zhi) p = fmaxf(p, pc[i]);
          const float contour = fmaxf(p - m_prev[i], 0.0f);
          o[i] = fmaxf(x_prev[i] - contour, 0.0f);
        }
        const size_t g = (size_t)zo * HW + b_off;
        if (last) {
          const float4 w = *(const float4*)(vo + g);
          sp += o[0] * w.x + o[1] * w.y + o[2] * w.z + o[3] * w.w;
          ss += o[0] + o[1] + o[2] + o[3];
        } else {
          *(float4*)(vd + g) = {o[0], o[1], o[2], o[3]};
        }
      }
      #pragma unroll
      for (int i = 0; i < 4; ++i) {
        p_mm[i] = p_m[i];
        p_m[i] = pc[i];
        m_prev[i] = v[i + 1];        // M(z-1) center (own M-role regs)
        x_prev[i] = c_mm.a[i + 2];   // x(z-1) center (post-rotation cache)
      }
    }
  }

  if (last) {
    #pragma unroll
    for (int off = 32; off > 0; off >>= 1) {
      sp += __shfl_down(sp, off, 64);
      ss += __shfl_down(ss, off, 64);
    }
    if (lane == 0) {
      red[wave] = (double)sp;
      red[4 + wave] = (double)ss;
    }
    __syncthreads();
    if (tid == 0) {
      const double a = red[0] + red[1] + red[2] + red[3];
      const double s2 = red[4] + red[5] + red[6] + red[7];
      const int lin = ((b * nch + chunk) * 24 + blockIdx.y) * 3 + blockIdx.x;
      part[2 * lin] = a;
      part[2 * lin + 1] = s2;
    }
  }
}

__global__ void finalize_kernel(const double* __restrict__ pa,
                                const double* __restrict__ pb,
                                float* __restrict__ out, int npart) {
  __shared__ double red[4][4];
  double s[4] = {0, 0, 0, 0};
  for (int i = threadIdx.x; i < npart; i += 256) {
    s[0] += pa[2 * i];
    s[1] += pa[2 * i + 1];
    s[2] += pb[2 * i];
    s[3] += pb[2 * i + 1];
  }
  #pragma unroll
  for (int off = 32; off > 0; off >>= 1)
    #pragma unroll
    for (int j = 0; j < 4; ++j) s[j] += __shfl_down(s[j], off, 64);
  const int wave = threadIdx.x >> 6, lane = threadIdx.x & 63;
  if (lane == 0)
    for (int j = 0; j < 4; ++j) red[j][wave] = s[j];
  __syncthreads();
  if (threadIdx.x == 0) {
    double t[4];
    for (int j = 0; j < 4; ++j)
      t[j] = red[j][0] + red[j][1] + red[j][2] + red[j][3];
    const double recall = (t[0] + 1e-12) / (t[1] + 1e-12);
    const double accv = (t[2] + 1e-12) / (t[3] + 1e-12);
    const double cldice = 2.0 * recall * accv / (recall + accv);
    out[0] = (float)(1.0 - cldice);
  }
}

extern "C" void kernel_launch(void* const* d_in, const int* in_sizes, int n_in,
                              void* d_out, int out_size, void* d_ws, size_t ws_size,
                              hipStream_t stream) {
  const float* pred = (const float*)d_in[0];
  const float* target = (const float*)d_in[1];
  float* out = (float*)d_out;
  const size_t NT = (size_t)VOL * B;

  const size_t need_merged = 4 * NT * sizeof(float) + 4 * MAXPART * sizeof(double);
  const dim3 blk(256, 1, 1);
  const int cz = CZ, nch = NCH;
  const int npart = 3 * 24 * nch * B;   // 864 per chain

  if (ws_size >= need_merged) {
    float* a0 = (float*)d_ws;
    float* a1 = a0 + NT;
    float* c0 = a1 + NT;
    float* c1 = c0 + NT;
    double* pA = (double*)(c1 + NT);
    double* pB = pA + 2 * MAXPART;
    const dim3 grd(3, 24, nch * B * 2);   // 1728 blocks
    skel_iter<<<grd, blk, 0, stream>>>(target, a0, pred, pA, pred, c0, target, pB, cz, nch, 0);
    skel_iter<<<grd, blk, 0, stream>>>(a0, a1, pred, pA, c0, c1, target, pB, cz, nch, 0);
    skel_iter<<<grd, blk, 0, stream>>>(a1, a0, pred, pA, c1, c0, target, pB, cz, nch, 0);
    skel_iter<<<grd, blk, 0, stream>>>(a0, a1, pred, pA, c0, c1, target, pB, cz, nch, 0);
    skel_iter<<<grd, blk, 0, stream>>>(a1, a0, pred, pA, c1, c0, target, pB, cz, nch, 1);
    finalize_kernel<<<1, 256, 0, stream>>>(pA, pB, out, npart);
  } else {
    float* b0 = (float*)d_ws;
    float* b1 = b0 + NT;
    double* pA = (double*)(b1 + NT);
    double* pB = pA + 2 * MAXPART;
    const dim3 grd(3, 24, nch * B);
    skel_iter<<<grd, blk, 0, stream>>>(target, b0, pred, pA, nullptr, nullptr, nullptr, nullptr, cz, nch, 0);
    skel_iter<<<grd, blk, 0, stream>>>(b0, b1, pred, pA, nullptr, nullptr, nullptr, nullptr, cz, nch, 0);
    skel_iter<<<grd, blk, 0, stream>>>(b1, b0, pred, pA, nullptr, nullptr, nullptr, nullptr, cz, nch, 0);
    skel_iter<<<grd, blk, 0, stream>>>(b0, b1, pred, pA, nullptr, nullptr, nullptr, nullptr, cz, nch, 0);
    skel_iter<<<grd, blk, 0, stream>>>(b1, b0, pred, pA, nullptr, nullptr, nullptr, nullptr, cz, nch, 1);
    skel_iter<<<grd, blk, 0, stream>>>(pred, b0, target, pB, nullptr, nullptr, nullptr, nullptr, cz, nch, 0);
    skel_iter<<<grd, blk, 0, stream>>>(b0, b1, target, pB, nullptr, nullptr, nullptr, nullptr, cz, nch, 0);
    skel_iter<<<grd, blk, 0, stream>>>(b1, b0, target, pB, nullptr, nullptr, nullptr, nullptr, cz, nch, 0);
    skel_iter<<<grd, blk, 0, stream>>>(b0, b1, target, pB, nullptr, nullptr, nullptr, nullptr, cz, nch, 0);
    skel_iter<<<grd, blk, 0, stream>>>(b1, b0, target, pB, nullptr, nullptr, nullptr, nullptr, cz, nch, 1);
    finalize_kernel<<<1, 256, 0, stream>>>(pA, pB, out, npart);
  }
}